// Round 6
// baseline (194.483 us; speedup 1.0000x reference)
//
#include <hip/hip_runtime.h>
#include <math.h>

#define EPS  1e-6f
#define DD   256
#define NSUP 5
#define NQ   8
#define SEQ  13
#define L2E  1.44269504088896f
#define LN2  0.693147180559945f
#define NEP  2048            // episodes
#define NROW 16384           // NEP*NQ query rows
#define NCOL 2048            // anchor columns
#define RG   (NROW / 32)     // 512 row-groups (32 rows each)

typedef short bf16x8 __attribute__((ext_vector_type(8)));
typedef float f32x4  __attribute__((ext_vector_type(4)));

__device__ __forceinline__ ushort f2bf(float f) {
  union { float f; unsigned u; } v; v.f = f;
  unsigned r = v.u + 0x7FFFu + ((v.u >> 16) & 1u);   // round-to-nearest-even
  return (ushort)(r >> 16);
}
__device__ __forceinline__ float bf2f(short u) {
  union { unsigned u; float f; } v; v.u = ((unsigned)(unsigned short)u) << 16;
  return v.f;
}

// ---------------------------------------------------------------------------
// prep: anchors/queries in MFMA-fragment-SWIZZLED order (coalesced fragment
// loads in main): element (c,d) -> ushort index ((T*8+kk)*64 + quad*16 + lc)*8
// + j with T=c>>4, lc=c&15, kk=d>>5, quad=(d>>3)&3, j=d&7.
// cb[c] = -log2(e) * (sum(a^2) - 2*eps*sum(a)); row-constant cq cancels.
// Also zeroes accum / fincount / per-rowgroup arrival counters.
// ---------------------------------------------------------------------------
__global__ __launch_bounds__(256) void proto_prep(
    const float* __restrict__ x, float* __restrict__ cb,
    ushort* __restrict__ Asw, ushort* __restrict__ Qsw,
    float* __restrict__ accum, int* __restrict__ fincount,
    int* __restrict__ rgcount) {
  const int n = blockIdx.x, d = threadIdx.x;
  if (n == 0 && d == 0) { accum[0] = 0.f; accum[1] = 0.f; fincount[0] = 0; }
  if (d == 0 && n < RG) rgcount[n] = 0;
  const float* xr = x + (size_t)n * SEQ * DD;

  const int kk = d >> 5, quad = (d >> 3) & 3, j = d & 7;
  const size_t dpart = (size_t)kk * 64 + quad * 16;   // within-T part from d

  float a = 0.f;
  #pragma unroll
  for (int s = 0; s < NSUP; ++s) a += xr[s * DD + d];
  a *= 0.2f;
  Asw[(((size_t)(n >> 4) * 8 * 64) + dpart + (n & 15)) * 8 + j] = f2bf(a);

  float s1 = a, s2 = a * a;
  #pragma unroll
  for (int off = 32; off; off >>= 1) {
    s1 += __shfl_xor(s1, off);
    s2 += __shfl_xor(s2, off);
  }
  __shared__ float red[8];
  const int wid = d >> 6, lane = d & 63;
  if (lane == 0) { red[wid] = s1; red[wid + 4] = s2; }
  __syncthreads();
  if (d == 0) {
    float t1 = red[0] + red[1] + red[2] + red[3];
    float t2 = red[4] + red[5] + red[6] + red[7];
    cb[n] = -L2E * (t2 - 2.f * EPS * t1);
  }
  #pragma unroll
  for (int s = 0; s < NQ; ++s) {
    const int row = n * NQ + s;
    Qsw[(((size_t)(row >> 4) * 8 * 64) + dpart + (row & 15)) * 8 + j]
        = f2bf(xr[(NSUP + s) * DD + d]);
  }
}

// ---------------------------------------------------------------------------
// main: 1024 blocks x 256 threads. Block b -> rowgroup b>>1 (32 rows), col
// half b&1 (1024 cols). Wave w owns 16 col-tiles. Hot loop identical to the
// proven r4 shape (88 VGPR, ping-pong B+cb prefetch, 9-inst slot update).
// Cross-half combine: atomicExch partials + fence + arrival counter; the
// second arriver merges via coherent atomic reads, computes label logits
// (bf16 dot post-pass, identical rounding), accumulates; counter finalize.
// MFMA layouts (verified): A m=lane&15,k=quad*8+j ; B n=lane&15,k=quad*8+j ;
// C col=lane&15,row=quad*4+reg.
// ---------------------------------------------------------------------------
__global__ __launch_bounds__(256, 4) void proto_main(
    const ushort* __restrict__ Qsw, const ushort* __restrict__ Asw,
    const float* __restrict__ cb, const int* __restrict__ label,
    float* __restrict__ pm, float* __restrict__ ps, int* __restrict__ pb,
    int* __restrict__ rgcount,
    float* __restrict__ accum, int* __restrict__ fincount,
    float* __restrict__ out) {
  const int tid  = threadIdx.x;
  const int wid  = tid >> 6, lane = tid & 63;
  const int quad = lane >> 4, lcol = lane & 15;
  const int rg   = blockIdx.x >> 1;
  const int h    = blockIdx.x & 1;
  const int r0   = rg * 32;

  const bf16x8* qb = (const bf16x8*)Qsw;
  const bf16x8* bb = (const bf16x8*)Asw;

  // resident A fragments: 2 row-sets x 8 K-chunks (coalesced loads)
  bf16x8 af[2][8];
  #pragma unroll
  for (int set = 0; set < 2; ++set) {
    const size_t base = ((size_t)((r0 >> 4) + set) * 8) * 64 + lane;
    #pragma unroll
    for (int kk = 0; kk < 8; ++kk) af[set][kk] = qb[base + (size_t)kk * 64];
  }

  float m[2][4], s[2][4];
  int   bi[2][4];
  #pragma unroll
  for (int set = 0; set < 2; ++set)
    #pragma unroll
    for (int i = 0; i < 4; ++i) {
      m[set][i] = -1e30f; s[set][i] = 0.f; bi[set][i] = 0x7fffffff;
    }

  auto process = [&](int T, bf16x8* B, float cbv) {
    f32x4 c0 = {0.f, 0.f, 0.f, 0.f}, c1 = {0.f, 0.f, 0.f, 0.f};
    #pragma unroll
    for (int kk = 0; kk < 8; ++kk) {
      c0 = __builtin_amdgcn_mfma_f32_16x16x32_bf16(af[0][kk], B[kk], c0, 0, 0, 0);
      c1 = __builtin_amdgcn_mfma_f32_16x16x32_bf16(af[1][kk], B[kk], c1, 0, 0, 0);
    }
    const int colIdx = T * 16 + lcol;
    #pragma unroll
    for (int set = 0; set < 2; ++set) {
      #pragma unroll
      for (int i = 0; i < 4; ++i) {
        float cv = (set == 0) ? c0[i] : c1[i];
        float v2 = fmaf(cv, 2.f * L2E, cbv);     // log2-frame shifted logit
        float dv = v2 - m[set][i];
        bool  gt = dv > 0.f;
        float e  = exp2f(-fabsf(dv));            // single non-unit exp factor
        s[set][i]  = fmaf(s[set][i], gt ? e : 1.f, gt ? 1.f : e);
        m[set][i]  = fmaxf(m[set][i], v2);
        bi[set][i] = gt ? colIdx : bi[set][i];   // strict >: first max wins
      }
    }
  };

  const int T0 = h * 64 + wid * 16;             // 128 tiles of 16 cols total
  bf16x8 buf0[8], buf1[8];
  float  cb0, cb1;
  #pragma unroll
  for (int kk = 0; kk < 8; ++kk)
    buf0[kk] = bb[((size_t)T0 * 8 + (size_t)kk) * 64 + lane];
  cb0 = cb[T0 * 16 + lcol];

  #pragma unroll 1
  for (int t = 0; t < 16; t += 2) {
    {
      const int Tn = T0 + t + 1;                             // always valid
      #pragma unroll
      for (int kk = 0; kk < 8; ++kk)
        buf1[kk] = bb[((size_t)Tn * 8 + (size_t)kk) * 64 + lane];
      cb1 = cb[Tn * 16 + lcol];
    }
    process(T0 + t, buf0, cb0);
    {
      const int Tm = (t + 2 < 16) ? T0 + t + 2 : T0 + t + 1; // clamp tail
      #pragma unroll
      for (int kk = 0; kk < 8; ++kk)
        buf0[kk] = bb[((size_t)Tm * 8 + (size_t)kk) * 64 + lane];
      cb0 = cb[Tm * 16 + lcol];
    }
    process(T0 + t + 1, buf1, cb1);
  }

  // merge across the 16 lanes sharing rows (cols differ)
  #pragma unroll
  for (int mask = 1; mask < 16; mask <<= 1) {
    #pragma unroll
    for (int set = 0; set < 2; ++set)
      #pragma unroll
      for (int i = 0; i < 4; ++i) {
        float om = __shfl_xor(m[set][i], mask);
        float os = __shfl_xor(s[set][i], mask);
        int   oi = __shfl_xor(bi[set][i], mask);
        float nm = fmaxf(m[set][i], om);
        s[set][i] = s[set][i] * exp2f(m[set][i] - nm) + os * exp2f(om - nm);
        bool better = (om > m[set][i]) || (om == m[set][i] && oi < bi[set][i]);
        bi[set][i] = better ? oi : bi[set][i];
        m[set][i]  = nm;
      }
  }

  __shared__ float sm[4][32], ssh[4][32], slab[32];
  __shared__ int   sbi[4][32];
  __shared__ int   s_old;
  if (lcol == 0) {
    #pragma unroll
    for (int set = 0; set < 2; ++set)
      #pragma unroll
      for (int i = 0; i < 4; ++i) {
        int rl = set * 16 + quad * 4 + i;
        sm[wid][rl] = m[set][i]; ssh[wid][rl] = s[set][i]; sbi[wid][rl] = bi[set][i];
      }
  }
  __syncthreads();

  float mm = 0.f, sv = 0.f;
  int   b  = 0;
  if (tid < 32) {
    mm = sm[0][tid]; sv = ssh[0][tid]; b = sbi[0][tid];
    #pragma unroll
    for (int w = 1; w < 4; ++w) {            // stripes in ascending col order
      float om = sm[w][tid], os = ssh[w][tid];
      int   oi = sbi[w][tid];
      float nm = fmaxf(mm, om);
      sv = sv * exp2f(mm - nm) + os * exp2f(om - nm);
      bool better = (om > mm) || (om == mm && oi < b);
      b = better ? oi : b;
      mm = nm;
    }
    const int row = r0 + tid;
    // post this half's partial with device-scope atomics, then arrive
    atomicExch(&pm[h * NROW + row], mm);
    atomicExch(&ps[h * NROW + row], sv);
    atomicExch(&pb[h * NROW + row], b);
    __threadfence();
    if (tid == 0) s_old = atomicAdd(&rgcount[rg], 1);
  }
  __syncthreads();
  if (s_old == 0) return;                    // first arriver is done

  // -------- second arriver: merge halves + label logits + accumulate -------
  {
    // label-logit post-pass: 8 lanes per row (32 rows), bf16 dot with the
    // same rounding as the MFMA path.
    const int r = tid >> 3, l = tid & 7;
    const int row = r0 + r;
    const int lab = label[row >> 3];
    const size_t qbase = ((size_t)(row >> 4) * 8 + l) * 64 + (row & 15);
    const size_t abase = ((size_t)(lab >> 4) * 8 + l) * 64 + (lab & 15);
    float dot = 0.f;
    #pragma unroll
    for (int q16 = 0; q16 < 4; ++q16) {
      bf16x8 qv = qb[qbase + (size_t)q16 * 16];
      bf16x8 av = bb[abase + (size_t)q16 * 16];
      #pragma unroll
      for (int j = 0; j < 8; ++j) dot = fmaf(bf2f(qv[j]), bf2f(av[j]), dot);
    }
    #pragma unroll
    for (int mask = 1; mask < 8; mask <<= 1) dot += __shfl_xor(dot, mask);
    if (l == 0) slab[r] = fmaf(dot, 2.f * L2E, cb[lab]);  // shifted label logit
  }
  __syncthreads();

  if (tid < 32) {
    const int row = r0 + tid;
    const int oh  = 1 - h;
    // coherent reads of the partner half (device-scope RMW; partner's fence
    // precedes its counter bump, which we observed)
    float om = atomicAdd(&pm[oh * NROW + row], 0.f);
    float os = atomicAdd(&ps[oh * NROW + row], 0.f);
    int   oi = atomicAdd(&pb[oh * NROW + row], 0);
    float nm = fmaxf(mm, om);
    sv = sv * exp2f(mm - nm) + os * exp2f(om - nm);
    bool better = (om > mm) || (om == mm && oi < b);   // absolute col indices
    b  = better ? oi : b;
    mm = nm;

    const int lb  = label[row >> 3];
    float loss = LN2 * (mm + log2f(sv) - slab[tid]);
    float corr = (b == lb) ? 1.f : 0.f;
    #pragma unroll
    for (int mask = 16; mask; mask >>= 1) {   // xor stays closed in lanes 0..31
      loss += __shfl_xor(loss, mask);
      corr += __shfl_xor(corr, mask);
    }
    if (tid == 0) {
      atomicAdd(&accum[0], loss);
      atomicAdd(&accum[1], corr);
      __threadfence();
      if (atomicAdd(fincount, 1) == RG - 1) {
        out[0] = atomicAdd(&accum[0], 0.f) / (float)NROW;   // coherent reads
        out[1] = atomicAdd(&accum[1], 0.f) * 100.f / (float)NROW;
      }
    }
  }
}

// ---------------------------------------------------------------------------
extern "C" void kernel_launch(void* const* d_in, const int* in_sizes, int n_in,
                              void* d_out, int out_size, void* d_ws, size_t ws_size,
                              hipStream_t stream) {
  const float* x     = (const float*)d_in[0];
  const int*   label = (const int*)d_in[1];
  float* out = (float*)d_out;

  // ws layout (float-sized slots):
  // [0:2) accum | [2] fincount | [16,16+RG) rgcount | cb[NCOL] |
  // pm[2*NROW] | ps[2*NROW] | pb[2*NROW] (int) | Asw | Qsw (bf16)
  float* W        = (float*)d_ws;
  float* accum    = W;
  int*   fincount = (int*)(W + 2);
  int*   rgcount  = (int*)(W + 16);
  float* cb       = W + 16 + RG;
  float* pm       = cb + NCOL;
  float* ps       = pm + 2 * NROW;
  int*   pb       = (int*)(ps + 2 * NROW);
  ushort* Asw     = (ushort*)(pb + 2 * NROW);
  ushort* Qsw     = Asw + (size_t)NCOL * DD;

  hipLaunchKernelGGL(proto_prep, dim3(NEP), dim3(256), 0, stream,
                     x, cb, Asw, Qsw, accum, fincount, rgcount);
  hipLaunchKernelGGL(proto_main, dim3(RG * 2), dim3(256), 0, stream,
                     Qsw, Asw, cb, label, pm, ps, pb, rgcount,
                     accum, fincount, out);
}

// Round 7
// 145.409 us; speedup vs baseline: 1.3375x; 1.3375x over previous
//
#include <hip/hip_runtime.h>
#include <math.h>

#define EPS  1e-6f
#define DD   256
#define NSUP 5
#define NQ   8
#define SEQ  13
#define L2E  1.44269504088896f
#define LN2  0.693147180559945f
#define NEP  2048            // episodes
#define NROW 16384           // NEP*NQ query rows
#define NCOL 2048            // anchor columns
#define RG   (NROW / 32)     // 512 row-groups (32 rows each)

typedef short bf16x8 __attribute__((ext_vector_type(8)));
typedef float f32x4  __attribute__((ext_vector_type(4)));

__device__ __forceinline__ ushort f2bf(float f) {
  union { float f; unsigned u; } v; v.f = f;
  unsigned r = v.u + 0x7FFFu + ((v.u >> 16) & 1u);   // round-to-nearest-even
  return (ushort)(r >> 16);
}
__device__ __forceinline__ float bf2f(short u) {
  union { unsigned u; float f; } v; v.u = ((unsigned)(unsigned short)u) << 16;
  return v.f;
}

// ---------------------------------------------------------------------------
// prep: anchors/queries in MFMA-fragment-SWIZZLED order (coalesced fragment
// loads in main): element (c,d) -> ushort index ((T*8+kk)*64 + quad*16 + lc)*8
// + j with T=c>>4, lc=c&15, kk=d>>5, quad=(d>>3)&3, j=d&7.
// cb[c] = -log2(e) * (sum(a^2) - 2*eps*sum(a)); row-constant cq cancels.
// Also zeroes accum / fincount / per-rowgroup arrival counters.
// ---------------------------------------------------------------------------
__global__ __launch_bounds__(256) void proto_prep(
    const float* __restrict__ x, float* __restrict__ cb,
    ushort* __restrict__ Asw, ushort* __restrict__ Qsw,
    float* __restrict__ accum, int* __restrict__ fincount,
    int* __restrict__ rgcount) {
  const int n = blockIdx.x, d = threadIdx.x;
  if (n == 0 && d == 0) { accum[0] = 0.f; accum[1] = 0.f; fincount[0] = 0; }
  if (d == 0 && n < RG) rgcount[n] = 0;
  const float* xr = x + (size_t)n * SEQ * DD;

  const int kk = d >> 5, quad = (d >> 3) & 3, j = d & 7;
  const size_t dpart = (size_t)kk * 64 + quad * 16;   // within-T part from d

  float a = 0.f;
  #pragma unroll
  for (int s = 0; s < NSUP; ++s) a += xr[s * DD + d];
  a *= 0.2f;
  Asw[(((size_t)(n >> 4) * 8 * 64) + dpart + (n & 15)) * 8 + j] = f2bf(a);

  float s1 = a, s2 = a * a;
  #pragma unroll
  for (int off = 32; off; off >>= 1) {
    s1 += __shfl_xor(s1, off);
    s2 += __shfl_xor(s2, off);
  }
  __shared__ float red[8];
  const int wid = d >> 6, lane = d & 63;
  if (lane == 0) { red[wid] = s1; red[wid + 4] = s2; }
  __syncthreads();
  if (d == 0) {
    float t1 = red[0] + red[1] + red[2] + red[3];
    float t2 = red[4] + red[5] + red[6] + red[7];
    cb[n] = -L2E * (t2 - 2.f * EPS * t1);
  }
  #pragma unroll
  for (int s = 0; s < NQ; ++s) {
    const int row = n * NQ + s;
    Qsw[(((size_t)(row >> 4) * 8 * 64) + dpart + (row & 15)) * 8 + j]
        = f2bf(xr[(NSUP + s) * DD + d]);
  }
}

// ---------------------------------------------------------------------------
// main: 1024 blocks x 256 threads. Block b -> rowgroup b>>1 (32 rows), col
// half b&1 (1024 cols). Wave w owns 16 col-tiles. Hot loop identical to the
// proven r4 shape (88 VGPR, ping-pong B+cb prefetch, 9-inst slot update).
// __launch_bounds__(256,2): min-waves>=3 makes the allocator clamp to 64
// VGPRs and SPILL (r5/r6: 79 MB WRITE_SIZE) — occupancy must come from the
// grid (4 blocks/CU at 88 VGPR <= 128/wave), not the bound.
// Cross-half combine: atomicExch partials + fence + arrival counter; the
// second arriver merges via coherent atomic reads, computes label logits
// (bf16 dot post-pass, identical rounding), accumulates; counter finalize.
// MFMA layouts (verified): A m=lane&15,k=quad*8+j ; B n=lane&15,k=quad*8+j ;
// C col=lane&15,row=quad*4+reg.
// ---------------------------------------------------------------------------
__global__ __launch_bounds__(256, 2) void proto_main(
    const ushort* __restrict__ Qsw, const ushort* __restrict__ Asw,
    const float* __restrict__ cb, const int* __restrict__ label,
    float* __restrict__ pm, float* __restrict__ ps, int* __restrict__ pb,
    int* __restrict__ rgcount,
    float* __restrict__ accum, int* __restrict__ fincount,
    float* __restrict__ out) {
  const int tid  = threadIdx.x;
  const int wid  = tid >> 6, lane = tid & 63;
  const int quad = lane >> 4, lcol = lane & 15;
  const int rg   = blockIdx.x >> 1;
  const int h    = blockIdx.x & 1;
  const int r0   = rg * 32;

  const bf16x8* qb = (const bf16x8*)Qsw;
  const bf16x8* bb = (const bf16x8*)Asw;

  // resident A fragments: 2 row-sets x 8 K-chunks (coalesced loads)
  bf16x8 af[2][8];
  #pragma unroll
  for (int set = 0; set < 2; ++set) {
    const size_t base = ((size_t)((r0 >> 4) + set) * 8) * 64 + lane;
    #pragma unroll
    for (int kk = 0; kk < 8; ++kk) af[set][kk] = qb[base + (size_t)kk * 64];
  }

  float m[2][4], s[2][4];
  int   bi[2][4];
  #pragma unroll
  for (int set = 0; set < 2; ++set)
    #pragma unroll
    for (int i = 0; i < 4; ++i) {
      m[set][i] = -1e30f; s[set][i] = 0.f; bi[set][i] = 0x7fffffff;
    }

  auto process = [&](int T, bf16x8* B, float cbv) {
    f32x4 c0 = {0.f, 0.f, 0.f, 0.f}, c1 = {0.f, 0.f, 0.f, 0.f};
    #pragma unroll
    for (int kk = 0; kk < 8; ++kk) {
      c0 = __builtin_amdgcn_mfma_f32_16x16x32_bf16(af[0][kk], B[kk], c0, 0, 0, 0);
      c1 = __builtin_amdgcn_mfma_f32_16x16x32_bf16(af[1][kk], B[kk], c1, 0, 0, 0);
    }
    const int colIdx = T * 16 + lcol;
    #pragma unroll
    for (int set = 0; set < 2; ++set) {
      #pragma unroll
      for (int i = 0; i < 4; ++i) {
        float cv = (set == 0) ? c0[i] : c1[i];
        float v2 = fmaf(cv, 2.f * L2E, cbv);     // log2-frame shifted logit
        float dv = v2 - m[set][i];
        bool  gt = dv > 0.f;
        float e  = exp2f(-fabsf(dv));            // single non-unit exp factor
        s[set][i]  = fmaf(s[set][i], gt ? e : 1.f, gt ? 1.f : e);
        m[set][i]  = fmaxf(m[set][i], v2);
        bi[set][i] = gt ? colIdx : bi[set][i];   // strict >: first max wins
      }
    }
  };

  const int T0 = h * 64 + wid * 16;             // 128 tiles of 16 cols total
  bf16x8 buf0[8], buf1[8];
  float  cb0, cb1;
  #pragma unroll
  for (int kk = 0; kk < 8; ++kk)
    buf0[kk] = bb[((size_t)T0 * 8 + (size_t)kk) * 64 + lane];
  cb0 = cb[T0 * 16 + lcol];

  #pragma unroll 1
  for (int t = 0; t < 16; t += 2) {
    {
      const int Tn = T0 + t + 1;                             // always valid
      #pragma unroll
      for (int kk = 0; kk < 8; ++kk)
        buf1[kk] = bb[((size_t)Tn * 8 + (size_t)kk) * 64 + lane];
      cb1 = cb[Tn * 16 + lcol];
    }
    process(T0 + t, buf0, cb0);
    {
      const int Tm = (t + 2 < 16) ? T0 + t + 2 : T0 + t + 1; // clamp tail
      #pragma unroll
      for (int kk = 0; kk < 8; ++kk)
        buf0[kk] = bb[((size_t)Tm * 8 + (size_t)kk) * 64 + lane];
      cb0 = cb[Tm * 16 + lcol];
    }
    process(T0 + t + 1, buf1, cb1);
  }

  // merge across the 16 lanes sharing rows (cols differ)
  #pragma unroll
  for (int mask = 1; mask < 16; mask <<= 1) {
    #pragma unroll
    for (int set = 0; set < 2; ++set)
      #pragma unroll
      for (int i = 0; i < 4; ++i) {
        float om = __shfl_xor(m[set][i], mask);
        float os = __shfl_xor(s[set][i], mask);
        int   oi = __shfl_xor(bi[set][i], mask);
        float nm = fmaxf(m[set][i], om);
        s[set][i] = s[set][i] * exp2f(m[set][i] - nm) + os * exp2f(om - nm);
        bool better = (om > m[set][i]) || (om == m[set][i] && oi < bi[set][i]);
        bi[set][i] = better ? oi : bi[set][i];
        m[set][i]  = nm;
      }
  }

  __shared__ float sm[4][32], ssh[4][32], slab[32];
  __shared__ int   sbi[4][32];
  __shared__ int   s_old;
  if (lcol == 0) {
    #pragma unroll
    for (int set = 0; set < 2; ++set)
      #pragma unroll
      for (int i = 0; i < 4; ++i) {
        int rl = set * 16 + quad * 4 + i;
        sm[wid][rl] = m[set][i]; ssh[wid][rl] = s[set][i]; sbi[wid][rl] = bi[set][i];
      }
  }
  __syncthreads();

  float mm = 0.f, sv = 0.f;
  int   b  = 0;
  if (tid < 32) {
    mm = sm[0][tid]; sv = ssh[0][tid]; b = sbi[0][tid];
    #pragma unroll
    for (int w = 1; w < 4; ++w) {            // stripes in ascending col order
      float om = sm[w][tid], os = ssh[w][tid];
      int   oi = sbi[w][tid];
      float nm = fmaxf(mm, om);
      sv = sv * exp2f(mm - nm) + os * exp2f(om - nm);
      bool better = (om > mm) || (om == mm && oi < b);
      b = better ? oi : b;
      mm = nm;
    }
    const int row = r0 + tid;
    // post this half's partial with device-scope atomics, then arrive
    atomicExch(&pm[h * NROW + row], mm);
    atomicExch(&ps[h * NROW + row], sv);
    atomicExch(&pb[h * NROW + row], b);
    __threadfence();
    if (tid == 0) s_old = atomicAdd(&rgcount[rg], 1);
  }
  __syncthreads();
  if (s_old == 0) return;                    // first arriver is done

  // -------- second arriver: merge halves + label logits + accumulate -------
  {
    // label-logit post-pass: 8 lanes per row (32 rows), bf16 dot with the
    // same rounding as the MFMA path.
    const int r = tid >> 3, l = tid & 7;
    const int row = r0 + r;
    const int lab = label[row >> 3];
    const size_t qbase = ((size_t)(row >> 4) * 8 + l) * 64 + (row & 15);
    const size_t abase = ((size_t)(lab >> 4) * 8 + l) * 64 + (lab & 15);
    float dot = 0.f;
    #pragma unroll
    for (int q16 = 0; q16 < 4; ++q16) {
      bf16x8 qv = qb[qbase + (size_t)q16 * 16];
      bf16x8 av = bb[abase + (size_t)q16 * 16];
      #pragma unroll
      for (int j = 0; j < 8; ++j) dot = fmaf(bf2f(qv[j]), bf2f(av[j]), dot);
    }
    #pragma unroll
    for (int mask = 1; mask < 8; mask <<= 1) dot += __shfl_xor(dot, mask);
    if (l == 0) slab[r] = fmaf(dot, 2.f * L2E, cb[lab]);  // shifted label logit
  }
  __syncthreads();

  if (tid < 32) {
    const int row = r0 + tid;
    const int oh  = 1 - h;
    // coherent reads of the partner half (device-scope RMW; partner's fence
    // precedes its counter bump, which we observed)
    float om = atomicAdd(&pm[oh * NROW + row], 0.f);
    float os = atomicAdd(&ps[oh * NROW + row], 0.f);
    int   oi = atomicAdd(&pb[oh * NROW + row], 0);
    float nm = fmaxf(mm, om);
    sv = sv * exp2f(mm - nm) + os * exp2f(om - nm);
    bool better = (om > mm) || (om == mm && oi < b);   // absolute col indices
    b  = better ? oi : b;
    mm = nm;

    const int lb  = label[row >> 3];
    float loss = LN2 * (mm + log2f(sv) - slab[tid]);
    float corr = (b == lb) ? 1.f : 0.f;
    #pragma unroll
    for (int mask = 16; mask; mask >>= 1) {   // xor stays closed in lanes 0..31
      loss += __shfl_xor(loss, mask);
      corr += __shfl_xor(corr, mask);
    }
    if (tid == 0) {
      atomicAdd(&accum[0], loss);
      atomicAdd(&accum[1], corr);
      __threadfence();
      if (atomicAdd(fincount, 1) == RG - 1) {
        out[0] = atomicAdd(&accum[0], 0.f) / (float)NROW;   // coherent reads
        out[1] = atomicAdd(&accum[1], 0.f) * 100.f / (float)NROW;
      }
    }
  }
}

// ---------------------------------------------------------------------------
extern "C" void kernel_launch(void* const* d_in, const int* in_sizes, int n_in,
                              void* d_out, int out_size, void* d_ws, size_t ws_size,
                              hipStream_t stream) {
  const float* x     = (const float*)d_in[0];
  const int*   label = (const int*)d_in[1];
  float* out = (float*)d_out;

  // ws layout (float-sized slots):
  // [0:2) accum | [2] fincount | [16,16+RG) rgcount | cb[NCOL] |
  // pm[2*NROW] | ps[2*NROW] | pb[2*NROW] (int) | Asw | Qsw (bf16)
  float* W        = (float*)d_ws;
  float* accum    = W;
  int*   fincount = (int*)(W + 2);
  int*   rgcount  = (int*)(W + 16);
  float* cb       = W + 16 + RG;
  float* pm       = cb + NCOL;
  float* ps       = pm + 2 * NROW;
  int*   pb       = (int*)(ps + 2 * NROW);
  ushort* Asw     = (ushort*)(pb + 2 * NROW);
  ushort* Qsw     = Asw + (size_t)NCOL * DD;

  hipLaunchKernelGGL(proto_prep, dim3(NEP), dim3(256), 0, stream,
                     x, cb, Asw, Qsw, accum, fincount, rgcount);
  hipLaunchKernelGGL(proto_main, dim3(RG * 2), dim3(256), 0, stream,
                     Qsw, Asw, cb, label, pm, ps, pb, rgcount,
                     accum, fincount, out);
}

// Round 8
// 123.093 us; speedup vs baseline: 1.5800x; 1.1813x over previous
//
#include <hip/hip_runtime.h>
#include <math.h>

#define EPS  1e-6f
#define DD   256
#define NSUP 5
#define NQ   8
#define SEQ  13
#define L2E  1.44269504088896f
#define LN2  0.693147180559945f
#define NEP  2048            // episodes
#define NROW 16384           // NEP*NQ query rows
#define NCOL 2048            // anchor columns

typedef short bf16x8 __attribute__((ext_vector_type(8)));
typedef unsigned short u16x4 __attribute__((ext_vector_type(4)));
typedef float f32x4  __attribute__((ext_vector_type(4)));

__device__ __forceinline__ ushort f2bf(float f) {
  union { float f; unsigned u; } v; v.f = f;
  unsigned r = v.u + 0x7FFFu + ((v.u >> 16) & 1u);   // round-to-nearest-even
  return (ushort)(r >> 16);
}
__device__ __forceinline__ float bf2f(short u) {
  union { unsigned u; float f; } v; v.u = ((unsigned)(unsigned short)u) << 16;
  return v.f;
}

// ---------------------------------------------------------------------------
// prep (vectorized): 512 blocks x 256 threads; group g=tid>>6 owns episode
// n=bid*4+g, lane l=tid&63 owns d = 4l..4l+3 via float4 loads (coalesced
// 1 KB/wave) and ushort4 swizzled stores. Swizzle for element (c,d):
//   ushort idx = (((c>>4)*8 + (d>>5))*64 + ((d>>3)&3)*16 + (c&15))*8 + (d&7)
// (4 consecutive d share one ushort4 slot since d0%4==0).
// cb[c] = -log2(e)*(sum(a^2) - 2*eps*sum(a)); row-constant cq cancels in the
// loss. Wave-level reduction only (64 lanes = exactly one episode's d-range).
// ---------------------------------------------------------------------------
__global__ __launch_bounds__(256) void proto_prep(
    const float* __restrict__ x, float* __restrict__ cb,
    ushort* __restrict__ Asw, ushort* __restrict__ Qsw,
    float* __restrict__ accum, int* __restrict__ fincount) {
  const int tid = threadIdx.x, g = tid >> 6, l = tid & 63;
  const int n = blockIdx.x * 4 + g;
  if (blockIdx.x == 0 && tid == 0) { accum[0] = 0.f; accum[1] = 0.f; fincount[0] = 0; }

  const float4* xr4 = (const float4*)(x + (size_t)n * SEQ * DD);

  const int d0   = l * 4;
  const int kk   = d0 >> 5, quad = (d0 >> 3) & 3, j = d0 & 7;   // j in {0,4}
  const size_t chunk_d = (size_t)kk * 64 + (size_t)quad * 16;

  float4 a = {0.f, 0.f, 0.f, 0.f};
  #pragma unroll
  for (int s = 0; s < NSUP; ++s) {
    float4 v = xr4[s * 64 + l];
    a.x += v.x; a.y += v.y; a.z += v.z; a.w += v.w;
  }
  a.x *= 0.2f; a.y *= 0.2f; a.z *= 0.2f; a.w *= 0.2f;
  {
    const size_t idx = (((size_t)(n >> 4) * 8) * 64 + chunk_d + (n & 15)) * 8 + j;
    u16x4 o = {f2bf(a.x), f2bf(a.y), f2bf(a.z), f2bf(a.w)};
    *(u16x4*)(Asw + idx) = o;
  }
  float s1 = a.x + a.y + a.z + a.w;
  float s2 = a.x * a.x + a.y * a.y + a.z * a.z + a.w * a.w;
  #pragma unroll
  for (int off = 32; off; off >>= 1) {
    s1 += __shfl_xor(s1, off);
    s2 += __shfl_xor(s2, off);
  }
  if (l == 0) cb[n] = -L2E * (s2 - 2.f * EPS * s1);

  #pragma unroll
  for (int s = 0; s < NQ; ++s) {
    float4 q = xr4[(NSUP + s) * 64 + l];
    const int row = n * NQ + s;
    const size_t idx = (((size_t)(row >> 4) * 8) * 64 + chunk_d + (row & 15)) * 8 + j;
    u16x4 o = {f2bf(q.x), f2bf(q.y), f2bf(q.z), f2bf(q.w)};
    *(u16x4*)(Qsw + idx) = o;
  }
}

// ---------------------------------------------------------------------------
// main: r4's proven 54-us config (512 blocks x 256 threads, wave w owns col
// stripe [w*512,+512) = 32 tiles, 88 VGPR, single pass, launch_bounds(256,2)
// — min-waves>=3 clamps VGPRs to 64 and spills 79 MB, r5/r6) with one trim:
// label-logit tracking removed from the hot loop (11 -> 9 inst/slot); label
// logit recomputed via the r6/r7-proven 8-lane bf16 dot post-pass (identical
// rounding to the MFMA path). MFMA layouts (verified): A m=lane&15,k=quad*8+j;
// B n=lane&15,k=quad*8+j ; C col=lane&15,row=quad*4+reg.
// ---------------------------------------------------------------------------
__global__ __launch_bounds__(256, 2) void proto_main(
    const ushort* __restrict__ Qsw, const ushort* __restrict__ Asw,
    const float* __restrict__ cb, const int* __restrict__ label,
    float* __restrict__ accum, int* __restrict__ fincount,
    float* __restrict__ out) {
  const int tid  = threadIdx.x;
  const int wid  = tid >> 6, lane = tid & 63;
  const int quad = lane >> 4, lcol = lane & 15;
  const int r0   = blockIdx.x * 32;

  const bf16x8* qb = (const bf16x8*)Qsw;
  const bf16x8* bb = (const bf16x8*)Asw;

  // resident A fragments: 2 row-sets x 8 K-chunks (coalesced loads)
  bf16x8 af[2][8];
  #pragma unroll
  for (int set = 0; set < 2; ++set) {
    const size_t base = ((size_t)((r0 >> 4) + set) * 8) * 64 + lane;
    #pragma unroll
    for (int kk = 0; kk < 8; ++kk) af[set][kk] = qb[base + (size_t)kk * 64];
  }

  float m[2][4], s[2][4];
  int   bi[2][4];
  #pragma unroll
  for (int set = 0; set < 2; ++set)
    #pragma unroll
    for (int i = 0; i < 4; ++i) {
      m[set][i] = -1e30f; s[set][i] = 0.f; bi[set][i] = 0x7fffffff;
    }

  auto process = [&](int T, bf16x8* B) {
    f32x4 c0 = {0.f, 0.f, 0.f, 0.f}, c1 = {0.f, 0.f, 0.f, 0.f};
    #pragma unroll
    for (int kk = 0; kk < 8; ++kk) {
      c0 = __builtin_amdgcn_mfma_f32_16x16x32_bf16(af[0][kk], B[kk], c0, 0, 0, 0);
      c1 = __builtin_amdgcn_mfma_f32_16x16x32_bf16(af[1][kk], B[kk], c1, 0, 0, 0);
    }
    const int   colIdx = T * 16 + lcol;
    const float cbv    = cb[colIdx];       // 64-B broadcast segment
    #pragma unroll
    for (int set = 0; set < 2; ++set) {
      #pragma unroll
      for (int i = 0; i < 4; ++i) {
        float cv = (set == 0) ? c0[i] : c1[i];
        float v2 = fmaf(cv, 2.f * L2E, cbv);     // log2-frame shifted logit
        float dv = v2 - m[set][i];
        bool  gt = dv > 0.f;
        float e  = exp2f(-fabsf(dv));            // single non-unit exp factor
        s[set][i]  = fmaf(s[set][i], gt ? e : 1.f, gt ? 1.f : e);
        m[set][i]  = fmaxf(m[set][i], v2);
        bi[set][i] = gt ? colIdx : bi[set][i];   // strict >: first max wins
      }
    }
  };

  const int T0 = wid * 32;
  bf16x8 buf0[8], buf1[8];
  #pragma unroll
  for (int kk = 0; kk < 8; ++kk)
    buf0[kk] = bb[((size_t)T0 * 8 + (size_t)kk) * 64 + lane];

  #pragma unroll 1
  for (int t = 0; t < 32; t += 2) {
    {
      const int Tn = T0 + t + 1;                             // always valid
      #pragma unroll
      for (int kk = 0; kk < 8; ++kk)
        buf1[kk] = bb[((size_t)Tn * 8 + (size_t)kk) * 64 + lane];
    }
    process(T0 + t, buf0);
    {
      const int Tm = (t + 2 < 32) ? T0 + t + 2 : T0 + t + 1; // clamp tail
      #pragma unroll
      for (int kk = 0; kk < 8; ++kk)
        buf0[kk] = bb[((size_t)Tm * 8 + (size_t)kk) * 64 + lane];
    }
    process(T0 + t + 1, buf1);
  }

  // merge across the 16 lanes sharing rows (cols differ)
  #pragma unroll
  for (int mask = 1; mask < 16; mask <<= 1) {
    #pragma unroll
    for (int set = 0; set < 2; ++set)
      #pragma unroll
      for (int i = 0; i < 4; ++i) {
        float om = __shfl_xor(m[set][i], mask);
        float os = __shfl_xor(s[set][i], mask);
        int   oi = __shfl_xor(bi[set][i], mask);
        float nm = fmaxf(m[set][i], om);
        s[set][i] = s[set][i] * exp2f(m[set][i] - nm) + os * exp2f(om - nm);
        bool better = (om > m[set][i]) || (om == m[set][i] && oi < bi[set][i]);
        bi[set][i] = better ? oi : bi[set][i];
        m[set][i]  = nm;
      }
  }

  __shared__ float sm[4][32], ssh[4][32], slab[32];
  __shared__ int   sbi[4][32];
  if (lcol == 0) {
    #pragma unroll
    for (int set = 0; set < 2; ++set)
      #pragma unroll
      for (int i = 0; i < 4; ++i) {
        int rl = set * 16 + quad * 4 + i;
        sm[wid][rl] = m[set][i]; ssh[wid][rl] = s[set][i]; sbi[wid][rl] = bi[set][i];
      }
  }

  // label-logit post-pass (r6/r7-proven): 8 lanes per row, 32 rows; bf16 dot
  // with the same rounding as the MFMA path.
  {
    const int r = tid >> 3, l = tid & 7;
    const int row = r0 + r;
    const int lab = label[row >> 3];
    const size_t qbase = ((size_t)(row >> 4) * 8 + l) * 64 + (row & 15);
    const size_t abase = ((size_t)(lab >> 4) * 8 + l) * 64 + (lab & 15);
    float dot = 0.f;
    #pragma unroll
    for (int q16 = 0; q16 < 4; ++q16) {
      bf16x8 qv = qb[qbase + (size_t)q16 * 16];
      bf16x8 av = bb[abase + (size_t)q16 * 16];
      #pragma unroll
      for (int j = 0; j < 8; ++j) dot = fmaf(bf2f(qv[j]), bf2f(av[j]), dot);
    }
    #pragma unroll
    for (int mask = 1; mask < 8; mask <<= 1) dot += __shfl_xor(dot, mask);
    if (l == 0) slab[r] = fmaf(dot, 2.f * L2E, cb[lab]);  // shifted label logit
  }
  __syncthreads();

  if (tid < 32) {
    float mm = sm[0][tid], sv = ssh[0][tid];
    int   b  = sbi[0][tid];
    #pragma unroll
    for (int w = 1; w < 4; ++w) {            // stripes in ascending col order
      float om = sm[w][tid], os = ssh[w][tid];
      int   oi = sbi[w][tid];
      float nm = fmaxf(mm, om);
      sv = sv * exp2f(mm - nm) + os * exp2f(om - nm);
      bool better = (om > mm) || (om == mm && oi < b);
      b = better ? oi : b;
      mm = nm;
    }
    const int row = r0 + tid;
    const int lb  = label[row >> 3];
    float loss = LN2 * (mm + log2f(sv) - slab[tid]);
    float corr = (b == lb) ? 1.f : 0.f;
    #pragma unroll
    for (int mask = 16; mask; mask >>= 1) {   // xor stays closed in lanes 0..31
      loss += __shfl_xor(loss, mask);
      corr += __shfl_xor(corr, mask);
    }
    if (tid == 0) {
      atomicAdd(&accum[0], loss);
      atomicAdd(&accum[1], corr);
      __threadfence();
      if (atomicAdd(fincount, 1) == (int)gridDim.x - 1) {
        out[0] = atomicAdd(&accum[0], 0.f) / (float)NROW;   // coherent reads
        out[1] = atomicAdd(&accum[1], 0.f) * 100.f / (float)NROW;
      }
    }
  }
}

// ---------------------------------------------------------------------------
extern "C" void kernel_launch(void* const* d_in, const int* in_sizes, int n_in,
                              void* d_out, int out_size, void* d_ws, size_t ws_size,
                              hipStream_t stream) {
  const float* x     = (const float*)d_in[0];
  const int*   label = (const int*)d_in[1];
  float* out = (float*)d_out;

  // ws layout (float-sized slots): [0:2) accum | [2] fincount |
  // [16,16+NCOL) cb | Asw (NCOL*DD ushort) | Qsw (NROW*DD ushort)
  float*  W        = (float*)d_ws;
  float*  accum    = W;
  int*    fincount = (int*)(W + 2);
  float*  cb       = W + 16;
  ushort* Asw      = (ushort*)(cb + NCOL);
  ushort* Qsw      = Asw + (size_t)NCOL * DD;

  hipLaunchKernelGGL(proto_prep, dim3(NEP / 4), dim3(256), 0, stream,
                     x, cb, Asw, Qsw, accum, fincount);
  hipLaunchKernelGGL(proto_main, dim3(NROW / 32), dim3(256), 0, stream,
                     Qsw, Asw, cb, label, accum, fincount, out);
}